// Round 11
// baseline (9741.242 us; speedup 1.0000x reference)
//
#include <hip/hip_runtime.h>

#define T_SEQ 512
#define BATCH 64
#define DIN0  512
#define D_H   1024
#define D_OUT 512
#define NBLK  256
#define TILES 65536   // 4rg * 64cb * 256 elems per exchange buffer

typedef __attribute__((ext_vector_type(8))) short short8;
typedef __attribute__((ext_vector_type(4))) float f32x4;

__device__ inline float bf2f(unsigned short u) {
    unsigned x = ((unsigned)u) << 16;
    return __builtin_bit_cast(float, x);
}
__device__ inline unsigned short f2bf(float f) {
    unsigned x = __builtin_bit_cast(unsigned, f);
    unsigned r = (x + 0x7fffu + ((x >> 16) & 1u)) >> 16;
    return (unsigned short)r;
}
__device__ inline float fast_sigmoid(float x) { return 1.f / (1.f + __expf(-x)); }
__device__ inline float fast_tanh(float x) {
    float ax = fabsf(x);
    float t = __expf(-2.f * ax);
    float r = (1.f - t) / (1.f + t);
    return copysignf(r, x);
}

// ---- coherence-point primitives (proven rounds 2/4/5/9) ----
__device__ inline void store_u16_sc01(void* p, unsigned v) {
    asm volatile("global_store_short %0, %1, off sc0 sc1" :: "v"(p), "v"(v) : "memory");
}
__device__ inline short8 load16_sc01(const void* p) {            // no wait (batched)
    short8 r;
    asm volatile("global_load_dwordx4 %0, %1, off sc0 sc1"
                 : "=&v"(r) : "v"(p) : "memory");
    return r;
}
__device__ inline short8 load16_sc01_wait(const void* p) {       // poll
    short8 r;
    asm volatile("global_load_dwordx4 %0, %1, off sc0 sc1\n\ts_waitcnt vmcnt(0)"
                 : "=&v"(r) : "v"(p) : "memory");
    return r;
}

#define MFMA16(a, b, c) __builtin_amdgcn_mfma_f32_16x16x32_bf16((a), (b), (c), 0, 0, 0)

// ---------------- cast fp32 -> bf16 ----------------
__global__ void cast_kernel(const float* __restrict__ in, unsigned short* __restrict__ out, int n4) {
    int i = blockIdx.x * blockDim.x + threadIdx.x;
    int stride = gridDim.x * blockDim.x;
    for (; i < n4; i += stride) {
        float4 v = ((const float4*)in)[i];
        ushort4 o;
        o.x = f2bf(v.x); o.y = f2bf(v.y); o.z = f2bf(v.z); o.w = f2bf(v.w);
        ((ushort4*)out)[i] = o;
    }
}

// ---------------- GRU layer scan: single wave, chunk-pipelined h-phase ----------------
// 256 blocks x 64 threads (R4 geometry). Block (rg,cb): rows rg*16..+16,
// cols cb*16..+16. Exchange tile-blocked [2][4*64][16][16] (R9-proven).
// h-phase split into 8 chunks of 128 K-cols: per chunk poll 8 flags ->
// load 4 reg fragments -> 12 MFMAs. Chunk order rotated by cb&7.
// FULLZ (L0): all 3 gates LDS-resident (147KB). else (L1): n,r full +
// z h-part resident (160KB); z x-part streamed from L2 in x-phase.
template <int DIN, bool FULLZ>
__global__ __launch_bounds__(64, 1) void gru_scan(
    const unsigned short* __restrict__ xseq,  // [T][B][DIN] row-major (L0: x; L1: y0)
    const unsigned short* __restrict__ wih,   // [3H][DIN] (r,z,n)
    const unsigned short* __restrict__ whh,   // [3H][H]
    const float* __restrict__ bih, const float* __restrict__ bhh,
    const float* __restrict__ h0,             // [B][H] fp32
    unsigned short* __restrict__ hbuf,        // [2][TILES] tile-blocked exchange
    unsigned short* __restrict__ Y,           // [T][B][H] row-major (cached)
    unsigned short* __restrict__ flags)       // [4 rg][64 cb] ushort
{
    extern __shared__ unsigned short lds[];
    constexpr int KT = 1024 + DIN;

    const int lane = threadIdx.x;
    const int bid  = blockIdx.x;
    const int xcd  = bid & 7;
    const int rg   = xcd >> 1;                      // rg pinned to 2 XCDs
    const int cb   = ((bid >> 3) << 1) | (xcd & 1); // 0..63
    const int c0   = cb * 16, r0 = rg * 16;
    const int tile = rg * 64 + cb;

    unsigned short* const frg   = flags + rg * 64;
    unsigned short* const myflg = frg + cb;

    // ---- stage weights into LDS (R4 layout: [gate][16][KT] swizzled) ----
    const int NG = FULLZ ? 3 : 2;
    for (int g = 0; g < NG; ++g) {
        const int grow = (g == 0) ? 2 * D_H : (g == 1 ? 0 : D_H);  // n, r, z
        unsigned short* W = lds + g * 16 * KT;
        for (int i = lane; i < 16 * 128; i += 64) {
            int c = i >> 7, kb = i & 127;
            int el = (c * KT + kb * 8) ^ ((c & 7) << 3);
            *(short8*)&W[el] = *(const short8*)&whh[(size_t)(grow + c0 + c) * D_H + kb * 8];
        }
        for (int i = lane; i < 16 * (DIN / 8); i += 64) {
            int c = i / (DIN / 8), kb = i % (DIN / 8);
            int el = (c * KT + 1024 + kb * 8) ^ ((c & 7) << 3);
            *(short8*)&W[el] = *(const short8*)&wih[(size_t)(grow + c0 + c) * DIN + kb * 8];
        }
    }
    if (!FULLZ) {   // z gate, h-part only: [16][1024] at slot 2
        for (int i = lane; i < 16 * 128; i += 64) {
            int c = i >> 7, kb = i & 127;
            int el = 32 * KT + ((c * 1024 + kb * 8) ^ ((c & 7) << 3));
            *(short8*)&lds[el] = *(const short8*)&whh[(size_t)(D_H + c0 + c) * D_H + kb * 8];
        }
    }

    const int arow = lane & 15;
    const int ako  = (lane >> 4) * 8;
    const int swz  = (arow & 7) << 3;
    const int gc   = c0 + arow;
    const int crow = (lane >> 4) * 4;

    const float b_r  = bih[gc] + bhh[gc];
    const float b_z  = bih[D_H + gc] + bhh[D_H + gc];
    const float b_xn = bih[2 * D_H + gc];
    const float b_hn = bhh[2 * D_H + gc];

    // ---- init h state, publish tile (buffer 0), flag=1 ----
    float hprev[4];
    #pragma unroll
    for (int i = 0; i < 4; ++i) {
        float v = h0[(size_t)(r0 + crow + i) * D_H + gc];
        hprev[i] = v;
        store_u16_sc01(&hbuf[tile * 256 + (crow + i) * 16 + arow], (unsigned)f2bf(v));
    }
    asm volatile("s_waitcnt vmcnt(0)" ::: "memory");
    if (lane == 0) store_u16_sc01(myflg, 1u);

    for (int t = 0; t < T_SEQ; ++t) {
        const unsigned short* hb  = hbuf + (t & 1) * TILES;
        unsigned short*       hbn = hbuf + ((t & 1) ^ 1) * TILES;
        const unsigned short* xt  = xseq + (size_t)t * BATCH * DIN;
        unsigned short*       Yt  = Y + (size_t)t * BATCH * D_H;

        f32x4 fr = {0.f,0.f,0.f,0.f}, fz = fr, fnx = fr, fnh = fr;

        // ---- x-phase (independent of h(t); hides peer jitter) ----
        #pragma unroll 4
        for (int k = 0; k < DIN; k += 32) {
            short8 a  = *(const short8*)&xt[(size_t)(r0 + arow) * DIN + k + ako];
            int el    = (arow * KT + 1024 + k + ako) ^ swz;
            short8 bn = *(const short8*)&lds[el];
            short8 br = *(const short8*)&lds[16 * KT + el];
            short8 bz;
            if (FULLZ) bz = *(const short8*)&lds[32 * KT + el];
            else       bz = *(const short8*)&wih[(size_t)(D_H + c0 + arow) * DIN + k + ako];
            fnx = MFMA16(a, bn, fnx);
            fr  = MFMA16(a, br, fr);
            fz  = MFMA16(a, bz, fz);
        }

        // ---- chunk-pipelined h-phase: 8 chunks x 128 K-cols ----
        for (int c = 0; c < 8; ++c) {
            const int ch = (c + (cb & 7)) & 7;
            // poll this chunk's 8 producer flags (one 16B line)
            {
                const unsigned short* fp = frg + ch * 8;
                for (int it = 0; it < 100000; ++it) {
                    short8 f = load16_sc01_wait(fp);
                    bool ok = true;
                    #pragma unroll
                    for (int j = 0; j < 8; ++j)
                        ok &= ((unsigned short)f[j] >= (unsigned)(t + 1));
                    if (__all(ok)) break;
                    __builtin_amdgcn_s_sleep(1);
                }
            }
            // load 4 fragments from the 8 ready tiles
            short8 hf[4];
            #pragma unroll
            for (int m = 0; m < 4; ++m) {
                int tk = rg * 64 + ch * 8 + m * 2 + (ako >> 4);
                hf[m] = load16_sc01(hb + (size_t)tk * 256 + arow * 16 + (ako & 8));
            }
            asm volatile("s_waitcnt vmcnt(0)" ::: "memory");
            __builtin_amdgcn_sched_barrier(0);
            // 12 MFMAs on this chunk
            #pragma unroll
            for (int m = 0; m < 4; ++m) {
                const int k = ch * 128 + m * 32;
                int el    = (arow * KT + k + ako) ^ swz;
                short8 bn = *(const short8*)&lds[el];
                short8 br = *(const short8*)&lds[16 * KT + el];
                short8 bz;
                if (FULLZ) bz = *(const short8*)&lds[32 * KT + el];
                else       bz = *(const short8*)&lds[32 * KT + ((arow * 1024 + k + ako) ^ swz)];
                fnh = MFMA16(hf[m], bn, fnh);
                fr  = MFMA16(hf[m], br, fr);
                fz  = MFMA16(hf[m], bz, fz);
            }
        }

        // ---- epilogue: gates + state; publish tile, flag, then Y ----
        unsigned short h16[4];
        #pragma unroll
        for (int i = 0; i < 4; ++i) {
            float r = fast_sigmoid(fr[i] + b_r);
            float z = fast_sigmoid(fz[i] + b_z);
            float n = fast_tanh(fnx[i] + b_xn + r * (fnh[i] + b_hn));
            float hn = (1.f - z) * n + z * hprev[i];
            hprev[i] = hn;
            h16[i] = f2bf(hn);
            store_u16_sc01(&hbn[tile * 256 + (crow + i) * 16 + arow], (unsigned)h16[i]);
        }
        asm volatile("s_waitcnt vmcnt(0)" ::: "memory");
        if (lane == 0) store_u16_sc01(myflg, (unsigned)(t + 2));
        #pragma unroll
        for (int i = 0; i < 4; ++i)
            Yt[(size_t)(r0 + crow + i) * D_H + gc] = h16[i];   // cached; next dispatch
    }
}

// ---------------- fused LayerNorm + output projection ----------------
__global__ __launch_bounds__(256) void ln_proj(
    const unsigned short* __restrict__ y1,   // [TB][1024] bf16
    const float* __restrict__ gamma, const float* __restrict__ beta,
    const unsigned short* __restrict__ ffw,  // [512][1024] bf16
    const float* __restrict__ ffb,           // [512]
    float* __restrict__ out)                 // [TB][512]
{
    __shared__ unsigned short ylds[16 * 1024];
    const int row0 = blockIdx.x * 16;
    const int tid = threadIdx.x;

    {
        const int rr = tid >> 4, l16 = tid & 15;
        const unsigned short* yrow = y1 + (size_t)(row0 + rr) * D_H;
        float s = 0.f, sq = 0.f;
        #pragma unroll
        for (int j8 = 0; j8 < 8; ++j8) {
            int k = l16 * 64 + j8 * 8;
            short8 v = *(const short8*)&yrow[k];
            int idx = (rr * 1024 + k) ^ ((rr & 7) << 3);
            *(short8*)&ylds[idx] = v;
            #pragma unroll
            for (int j = 0; j < 8; ++j) {
                float f = bf2f((unsigned short)v[j]);
                s += f; sq += f * f;
            }
        }
        #pragma unroll
        for (int o = 1; o < 16; o <<= 1) {
            s  += __shfl_xor(s, o, 64);
            sq += __shfl_xor(sq, o, 64);
        }
        float mu = s * (1.f / 1024.f);
        float var = sq * (1.f / 1024.f) - mu * mu;
        float rstd = rsqrtf(var + 1e-5f);
        #pragma unroll
        for (int j8 = 0; j8 < 8; ++j8) {
            int k = l16 * 64 + j8 * 8;
            int idx = (rr * 1024 + k) ^ ((rr & 7) << 3);
            short8 v = *(short8*)&ylds[idx];
            short8 o8;
            #pragma unroll
            for (int j = 0; j < 8; ++j) {
                float f = bf2f((unsigned short)v[j]);
                f = (f - mu) * rstd * gamma[k + j] + beta[k + j];
                o8[j] = (short)f2bf(f);
            }
            *(short8*)&ylds[idx] = o8;
        }
    }
    __syncthreads();

    const int w = tid >> 6, lane = tid & 63;
    const int cbase = w * 128;
    const int arow = lane & 15, ako = (lane >> 4) * 8;
    f32x4 acc[8] = {};
    for (int k = 0; k < D_H; k += 32) {
        int aidx = (arow * 1024 + k + ako) ^ ((arow & 7) << 3);
        short8 a = *(const short8*)&ylds[aidx];
        #pragma unroll
        for (int n = 0; n < 8; ++n) {
            int col = cbase + n * 16 + (lane & 15);
            short8 b = *(const short8*)&ffw[col * 1024 + k + ako];
            acc[n] = __builtin_amdgcn_mfma_f32_16x16x32_bf16(a, b, acc[n], 0, 0, 0);
        }
    }
    #pragma unroll
    for (int n = 0; n < 8; ++n) {
        int col = cbase + n * 16 + (lane & 15);
        float bb = ffb[col];
        #pragma unroll
        for (int i = 0; i < 4; ++i) {
            int rr = row0 + (lane >> 4) * 4 + i;
            out[(size_t)rr * D_OUT + col] = acc[n][i] + bb;
        }
    }
}

// ---------------- launch ----------------
extern "C" void kernel_launch(void* const* d_in, const int* in_sizes, int n_in,
                              void* d_out, int out_size, void* d_ws, size_t ws_size,
                              hipStream_t stream) {
    const float* x     = (const float*)d_in[0];
    const float* h     = (const float*)d_in[1];
    const float* w_ih0 = (const float*)d_in[2];
    const float* w_hh0 = (const float*)d_in[3];
    const float* b_ih0 = (const float*)d_in[4];
    const float* b_hh0 = (const float*)d_in[5];
    const float* w_ih1 = (const float*)d_in[6];
    const float* w_hh1 = (const float*)d_in[7];
    const float* b_ih1 = (const float*)d_in[8];
    const float* b_hh1 = (const float*)d_in[9];
    const float* ln_g  = (const float*)d_in[10];
    const float* ln_b  = (const float*)d_in[11];
    const float* ff_w  = (const float*)d_in[12];
    const float* ff_b  = (const float*)d_in[13];
    float* out = (float*)d_out;

    char* ws = (char*)d_ws;
    size_t off = 0;
    auto alloc = [&](size_t bytes) {
        void* p = ws + off;
        off = (off + bytes + 255) & ~(size_t)255;
        return p;
    };
    unsigned short* x_bf   = (unsigned short*)alloc((size_t)T_SEQ * BATCH * DIN0 * 2);
    unsigned short* y1_bf  = (unsigned short*)alloc((size_t)T_SEQ * BATCH * D_H * 2);
    unsigned short* wih0_b = (unsigned short*)alloc((size_t)3 * D_H * DIN0 * 2);
    unsigned short* whh0_b = (unsigned short*)alloc((size_t)3 * D_H * D_H * 2);
    unsigned short* wih1_b = (unsigned short*)alloc((size_t)3 * D_H * D_H * 2);
    unsigned short* whh1_b = (unsigned short*)alloc((size_t)3 * D_H * D_H * 2);
    unsigned short* ffw_b  = (unsigned short*)alloc((size_t)D_OUT * D_H * 2);
    unsigned short* hbuf   = (unsigned short*)alloc((size_t)2 * TILES * 2);
    unsigned short* flags  = (unsigned short*)alloc(2 * 4 * 64 * 2);   // 1KB
    if (off > ws_size) return;

    unsigned short* y0_bf = (unsigned short*)d_out;  // 67MB staging, overwritten by ln_proj

    hipMemsetAsync(flags, 0, 2 * 4 * 64 * 2, stream);

    auto castl = [&](const float* src, unsigned short* dst, int n) {
        int n4 = n / 4;
        int blocks = (n4 + 255) / 256;
        if (blocks > 2048) blocks = 2048;
        hipLaunchKernelGGL(cast_kernel, dim3(blocks), dim3(256), 0, stream, src, dst, n4);
    };
    castl(x,     x_bf,   T_SEQ * BATCH * DIN0);
    castl(w_ih0, wih0_b, 3 * D_H * DIN0);
    castl(w_hh0, whh0_b, 3 * D_H * D_H);
    castl(w_ih1, wih1_b, 3 * D_H * D_H);
    castl(w_hh1, whh1_b, 3 * D_H * D_H);
    castl(ff_w,  ffw_b,  D_OUT * D_H);

    const int lds0 = 3 * 16 * (1024 + DIN0) * 2;                 // 147456
    const int lds1 = (2 * 16 * (1024 + D_H) + 16 * 1024) * 2;    // 163840
    hipFuncSetAttribute((const void*)&gru_scan<DIN0, true>,
                        hipFuncAttributeMaxDynamicSharedMemorySize, lds0);
    hipFuncSetAttribute((const void*)&gru_scan<D_H, false>,
                        hipFuncAttributeMaxDynamicSharedMemorySize, lds1);

    hipLaunchKernelGGL((gru_scan<DIN0, true>), dim3(NBLK), dim3(64), lds0, stream,
        x_bf, wih0_b, whh0_b, b_ih0, b_hh0, h, hbuf, y0_bf, flags);
    hipLaunchKernelGGL((gru_scan<D_H, false>), dim3(NBLK), dim3(64), lds1, stream,
        y0_bf, wih1_b, whh1_b, b_ih1, b_hh1, h + BATCH * D_H, hbuf, y1_bf,
        flags + 256);
    hipLaunchKernelGGL(ln_proj, dim3(T_SEQ * BATCH / 16), dim3(256), 0, stream,
        y1_bf, ln_g, ln_b, ffw_b, ff_b, out);
}